// Round 1
// baseline (97.738 us; speedup 1.0000x reference)
//
#include <hip/hip_runtime.h>

typedef float    f32x4 __attribute__((ext_vector_type(4)));
typedef _Float16 f16x8 __attribute__((ext_vector_type(8)));
typedef _Float16 f16x4 __attribute__((ext_vector_type(4)));

#define MFMA16 __builtin_amdgcn_mfma_f32_16x16x32_f16

#define NQ     400
#define DMODEL 768

// LDS layout (bytes)
#define K_OFF    0                  // K fp16 [400][64], 128B rows, XOR-swizzled
#define VT_OFF   51200              // V^T fp16 [64][424], 848B rows, cols 400..415 zeroed
#define SCR_OFF  105472             // phase2: P scratch, 4 waves x (16 rows x 832B) = 53248
#define W_OFF    SCR_OFF            // phase1: W fp16 x3, [64][72] rows (144B) -> 9216 each
#define QS_OFF   (SCR_OFF + 27648)  // phase1: Q transpose scratch, 4 waves x 2048B
#define MAS_OFF  158720             // mask f32 [400]
#define BIAS_OFF 160320             // bias f32 [3][64]
#define SMEM_BYTES 161088

__device__ __forceinline__ f16x8 cvt8(const float* rp) {
    f32x4 u0 = *(const f32x4*)(rp);
    f32x4 u1 = *(const f32x4*)(rp + 4);
    f16x8 a;
    a[0] = (_Float16)u0[0]; a[1] = (_Float16)u0[1];
    a[2] = (_Float16)u0[2]; a[3] = (_Float16)u0[3];
    a[4] = (_Float16)u1[0]; a[5] = (_Float16)u1[1];
    a[6] = (_Float16)u1[2]; a[7] = (_Float16)u1[3];
    return a;
}

__global__ __launch_bounds__(256, 1)
void attn_fused(const float* __restrict__ R, const float* __restrict__ Rmas,
                const float* __restrict__ Wq, const float* __restrict__ bq,
                const float* __restrict__ Wk, const float* __restrict__ bk,
                const float* __restrict__ Wv, const float* __restrict__ bv,
                float* __restrict__ out)
{
    extern __shared__ char smem[];
    const int tid  = threadIdx.x;
    const int lane = tid & 63;
    const int wv   = tid >> 6;
    const int g    = lane >> 4;
    const int q16  = lane & 15;

    const int blk  = blockIdx.x;
    const int b    = blk / 24;
    const int rem  = blk - b * 24;
    const int h    = rem >> 1;
    const int half = rem & 1;
    const int qlo   = half ? 13 : 0;
    const int ntile = half ? 12 : 13;

    // ---------- stage W (fp16, rows padded to 72), bias (f32), mask (f32) ----------
    {
        const float* Wms[3] = {Wq, Wk, Wv};
        const int row = tid >> 2;          // 0..63
        const int c0  = (tid & 3) << 4;    // 0,16,32,48
        #pragma unroll
        for (int m = 0; m < 3; ++m) {
            const float* Wm = Wms[m] + row * 64 + c0;
            #pragma unroll
            for (int j = 0; j < 4; ++j) {
                f32x4 v = *(const f32x4*)(Wm + 4 * j);
                f16x4 hv;
                hv[0]=(_Float16)v[0]; hv[1]=(_Float16)v[1];
                hv[2]=(_Float16)v[2]; hv[3]=(_Float16)v[3];
                *(f16x4*)(smem + W_OFF + m * 9216 + row * 144 + (c0 + 4 * j) * 2) = hv;
            }
        }
        if (tid < 192) {
            const float* bms[3] = {bq, bk, bv};
            *(float*)(smem + BIAS_OFF + tid * 4) = bms[tid >> 6][tid & 63];
        }
        for (int i = tid; i < NQ; i += 256)
            *(float*)(smem + MAS_OFF + i * 4) = Rmas[b * NQ + i];
        // zero-pad V^T cols 400..415 (64 rows x 32B; 256 threads x 8B)
        {
            const int r = tid >> 2, p = tid & 3;
            *(f16x4*)(smem + VT_OFF + r * 848 + 800 + p * 8) = (f16x4){0, 0, 0, 0};
        }
    }
    __syncthreads();

    const float* Rbh = R + (size_t)b * NQ * DMODEL + h * 64;

    // ---------- phase 1: K -> LDS (swizzled row-major), V^T -> LDS ----------
    #pragma unroll
    for (int tt = 0; tt < 7; ++tt) {
        const int t = wv + 4 * tt;
        if (t < 25) {
            const float* rp = Rbh + (size_t)(t * 16 + q16) * DMODEL + g * 8;
            f16x8 af0 = cvt8(rp);
            f16x8 af1 = cvt8(rp + 32);
            #pragma unroll
            for (int m = 1; m < 3; ++m) {
                #pragma unroll
                for (int cg = 0; cg < 4; ++cg) {
                    const int col = cg * 16 + q16;
                    const float bb = *(const float*)(smem + BIAS_OFF + (m * 64 + col) * 4);
                    f32x4 acc = {bb, bb, bb, bb};
                    f16x8 wb0 = *(const f16x8*)(smem + W_OFF + m * 9216 + col * 144 + g * 16);
                    f16x8 wb1 = *(const f16x8*)(smem + W_OFF + m * 9216 + col * 144 + 64 + g * 16);
                    acc = MFMA16(af0, wb0, acc, 0, 0, 0);
                    acc = MFMA16(af1, wb1, acc, 0, 0, 0);
                    if (m == 1) {
                        #pragma unroll
                        for (int r = 0; r < 4; ++r) {
                            const int kk = t * 16 + 4 * g + r;
                            *(_Float16*)(smem + K_OFF + kk * 128 + ((col * 2) ^ ((kk & 7) << 4))) =
                                (_Float16)acc[r];
                        }
                    } else {
                        f16x4 hv;
                        hv[0]=(_Float16)acc[0]; hv[1]=(_Float16)acc[1];
                        hv[2]=(_Float16)acc[2]; hv[3]=(_Float16)acc[3];
                        *(f16x4*)(smem + VT_OFF + col * 848 + (t * 16 + 4 * g) * 2) = hv;
                    }
                }
            }
        }
    }

    // ---------- phase 1c: this block's Q tiles -> register A-fragments ----------
    f16x8 qf[4][2];
    const int QSw = QS_OFF + wv * 2048;
    #pragma unroll
    for (int ti = 0; ti < 4; ++ti) {
        const int qi = wv + 4 * ti;
        if (qi < ntile) {
            const int qt = qlo + qi;
            const float* rp = Rbh + (size_t)(qt * 16 + q16) * DMODEL + g * 8;
            f16x8 af0 = cvt8(rp);
            f16x8 af1 = cvt8(rp + 32);
            #pragma unroll
            for (int cg = 0; cg < 4; ++cg) {
                const int col = cg * 16 + q16;
                const float bb = *(const float*)(smem + BIAS_OFF + col * 4);
                f32x4 acc = {bb, bb, bb, bb};
                f16x8 wb0 = *(const f16x8*)(smem + W_OFF + col * 144 + g * 16);
                f16x8 wb1 = *(const f16x8*)(smem + W_OFF + col * 144 + 64 + g * 16);
                acc = MFMA16(af0, wb0, acc, 0, 0, 0);
                acc = MFMA16(af1, wb1, acc, 0, 0, 0);
                #pragma unroll
                for (int r = 0; r < 4; ++r) {
                    const int rr = 4 * g + r;
                    *(_Float16*)(smem + QSw + rr * 128 + ((col * 2) ^ ((rr & 7) << 4))) =
                        (_Float16)acc[r];
                }
            }
            asm volatile("s_waitcnt lgkmcnt(0)" ::: "memory");
            qf[ti][0] = *(const f16x8*)(smem + QSw + q16 * 128 + (( g * 16      ) ^ ((q16 & 7) << 4)));
            qf[ti][1] = *(const f16x8*)(smem + QSw + q16 * 128 + ((64 + g * 16  ) ^ ((q16 & 7) << 4)));
        }
    }
    __syncthreads();

    // ---------- phase 2: attention ----------
    const int Pw = SCR_OFF + wv * 13312;
    // zero-pad P cols 400..415 once (16 rows x 32B; one 8B store per lane)
    *(f16x4*)(smem + Pw + q16 * 832 + 800 + g * 8) = (f16x4){0, 0, 0, 0};

    #pragma unroll
    for (int ti = 0; ti < 4; ++ti) {
        const int qi = wv + 4 * ti;
        if (qi < ntile) {
            const int qt = qlo + qi;
            float mq[4];
            #pragma unroll
            for (int r = 0; r < 4; ++r)
                mq[r] = *(const float*)(smem + MAS_OFF + (qt * 16 + 4 * g + r) * 4);

            // QK^T: 25 key tiles, K-dim 64 = 2 MFMAs
            f32x4 a[25];
            #pragma unroll
            for (int kt = 0; kt < 25; ++kt) {
                const int krow = kt * 16 + q16;
                f16x8 kf0 = *(const f16x8*)(smem + K_OFF + krow * 128 + (( g * 16     ) ^ ((krow & 7) << 4)));
                f16x8 kf1 = *(const f16x8*)(smem + K_OFF + krow * 128 + ((64 + g * 16 ) ^ ((krow & 7) << 4)));
                f32x4 acc = {0.f, 0.f, 0.f, 0.f};
                acc = MFMA16(qf[ti][0], kf0, acc, 0, 0, 0);
                acc = MFMA16(qf[ti][1], kf1, acc, 0, 0, 0);
                a[kt] = acc;
            }

            // mask before scale (faithful to reference), then row max
            float pm[4] = {-3e38f, -3e38f, -3e38f, -3e38f};
            #pragma unroll
            for (int kt = 0; kt < 25; ++kt) {
                const float mk = *(const float*)(smem + MAS_OFF + (kt * 16 + q16) * 4);
                #pragma unroll
                for (int r = 0; r < 4; ++r) {
                    const float x = (a[kt][r] - (1.0f - mq[r] * mk) * 100000.0f) * 0.125f;
                    a[kt][r] = x;
                    pm[r] = fmaxf(pm[r], x);
                }
            }
            #pragma unroll
            for (int s = 1; s <= 8; s <<= 1) {
                #pragma unroll
                for (int r = 0; r < 4; ++r)
                    pm[r] = fmaxf(pm[r], __shfl_xor(pm[r], s));
            }

            // exp + sum; unnormalized P -> per-wave LDS scratch (fp16)
            float ps[4] = {0.f, 0.f, 0.f, 0.f};
            #pragma unroll
            for (int kt = 0; kt < 25; ++kt) {
                #pragma unroll
                for (int r = 0; r < 4; ++r) {
                    const float p = __builtin_amdgcn_exp2f((a[kt][r] - pm[r]) * 1.4426950408889634f);
                    ps[r] += p;
                    *(_Float16*)(smem + Pw + (4 * g + r) * 832 + (kt * 16 + q16) * 2) = (_Float16)p;
                }
            }
            #pragma unroll
            for (int s = 1; s <= 8; s <<= 1) {
                #pragma unroll
                for (int r = 0; r < 4; ++r)
                    ps[r] += __shfl_xor(ps[r], s);
            }
            asm volatile("s_waitcnt lgkmcnt(0)" ::: "memory");

            // PV: 13 kk-chunks of 32 (400 + 16 zero pad)
            f32x4 oc[4];
            #pragma unroll
            for (int cg = 0; cg < 4; ++cg) oc[cg] = (f32x4){0.f, 0.f, 0.f, 0.f};
            #pragma unroll
            for (int kc = 0; kc < 13; ++kc) {
                f16x8 pa = *(const f16x8*)(smem + Pw + q16 * 832 + kc * 64 + g * 16);
                #pragma unroll
                for (int cg = 0; cg < 4; ++cg) {
                    f16x8 vb = *(const f16x8*)(smem + VT_OFF + (cg * 16 + q16) * 848 + kc * 64 + g * 16);
                    oc[cg] = MFMA16(pa, vb, oc[cg], 0, 0, 0);
                }
            }

            // epilogue: normalize by row-sum, apply query mask, store fp32
            #pragma unroll
            for (int r = 0; r < 4; ++r) {
                const float rs = mq[r] * __builtin_amdgcn_rcpf(ps[r]);
                float* op = out + (size_t)(b * NQ + qt * 16 + 4 * g + r) * DMODEL + h * 64;
                #pragma unroll
                for (int cg = 0; cg < 4; ++cg)
                    op[cg * 16 + q16] = oc[cg][r] * rs;
            }
        }
    }
}

extern "C" void kernel_launch(void* const* d_in, const int* in_sizes, int n_in,
                              void* d_out, int out_size, void* d_ws, size_t ws_size,
                              hipStream_t stream) {
    const float* R    = (const float*)d_in[0];
    const float* Rmas = (const float*)d_in[1];
    const float* Wq   = (const float*)d_in[2];
    const float* bq   = (const float*)d_in[3];
    const float* Wk   = (const float*)d_in[4];
    const float* bk   = (const float*)d_in[5];
    const float* Wv   = (const float*)d_in[6];
    const float* bv   = (const float*)d_in[7];
    float* out = (float*)d_out;

    (void)hipFuncSetAttribute(reinterpret_cast<const void*>(attn_fused),
                              hipFuncAttributeMaxDynamicSharedMemorySize, SMEM_BYTES);
    attn_fused<<<dim3(768), dim3(256), SMEM_BYTES, stream>>>(R, Rmas, Wq, bq, Wk, bk, Wv, bv, out);
}

// Round 2
// 60.156 us; speedup vs baseline: 1.6247x; 1.6247x over previous
//
#include <hip/hip_runtime.h>

typedef float    f32x4 __attribute__((ext_vector_type(4)));
typedef _Float16 f16x8 __attribute__((ext_vector_type(8)));
typedef _Float16 f16x4 __attribute__((ext_vector_type(4)));

#define MFMA16 __builtin_amdgcn_mfma_f32_16x16x32_f16

#define NQ     400
#define DMODEL 768

// mask-before-scale, folded with log2e for exp2:
// ref: softmax((S - (1-mq*mk)*1e5)/8); e^z = 2^(z*log2e)
#define SCL 0.18033688011112042f   /* 0.125 * log2(e) */
#define PEN 18033.688011112043f    /* 12500 * log2(e) */

// LDS layout (bytes)
#define K_OFF    0                  // K fp16 [400][64], 128B rows, XOR-swizzled by (row&7)<<4
#define VT_OFF   51200              // V^T fp16 [64][424], 848B rows, k block-permuted; 54272B
#define W_OFF    105472             // W fp16 x3, [64] rows of 144B -> 9216 each; 27648B
#define QS_OFF   133120             // Q transpose scratch, 8 waves x 2048B
#define MAS_OFF  149504             // mask f32 [400]
#define BIAS_OFF 151104             // bias f32 [3][64]
#define MKB_OFF  151872             // mask bits, 16 u32
#define SMEM_BYTES 151936

__device__ __forceinline__ f16x8 cvt8(const float* rp) {
    f32x4 u0 = *(const f32x4*)(rp);
    f32x4 u1 = *(const f32x4*)(rp + 4);
    f16x8 a;
    a[0] = (_Float16)u0[0]; a[1] = (_Float16)u0[1];
    a[2] = (_Float16)u0[2]; a[3] = (_Float16)u0[3];
    a[4] = (_Float16)u1[0]; a[5] = (_Float16)u1[1];
    a[6] = (_Float16)u1[2]; a[7] = (_Float16)u1[3];
    return a;
}

__global__ __launch_bounds__(512, 2)
void attn_fused(const float* __restrict__ R, const float* __restrict__ Rmas,
                const float* __restrict__ Wq, const float* __restrict__ bq,
                const float* __restrict__ Wk, const float* __restrict__ bk,
                const float* __restrict__ Wv, const float* __restrict__ bv,
                float* __restrict__ out)
{
    extern __shared__ char smem[];
    const int tid  = threadIdx.x;
    const int lane = tid & 63;
    const int wv   = tid >> 6;      // 0..7
    const int g    = lane >> 4;
    const int q16  = lane & 15;

    const int blk = blockIdx.x;
    const int b   = blk / 12;
    const int h   = blk % 12;

    // ---------- phase 0: stage W (fp16), bias, mask floats, mask bits; zero-pad VT ----------
    {
        const float* Wms[3] = {Wq, Wk, Wv};
        const int row = tid >> 3;          // 0..63
        const int c0  = (tid & 7) << 3;    // 0..56
        #pragma unroll
        for (int m = 0; m < 3; ++m) {
            const float* Wm = Wms[m] + row * 64 + c0;
            f32x4 v0 = *(const f32x4*)(Wm);
            f32x4 v1 = *(const f32x4*)(Wm + 4);
            f16x8 hv;
            hv[0]=(_Float16)v0[0]; hv[1]=(_Float16)v0[1];
            hv[2]=(_Float16)v0[2]; hv[3]=(_Float16)v0[3];
            hv[4]=(_Float16)v1[0]; hv[5]=(_Float16)v1[1];
            hv[6]=(_Float16)v1[2]; hv[7]=(_Float16)v1[3];
            *(f16x8*)(smem + W_OFF + m * 9216 + row * 144 + c0 * 2) = hv;
        }
        if (tid < 192) {
            const float* bms[3] = {bq, bk, bv};
            *(float*)(smem + BIAS_OFF + tid * 4) = bms[tid >> 6][tid & 63];
        }
        if (tid < NQ)
            *(float*)(smem + MAS_OFF + tid * 4) = Rmas[b * NQ + tid];
        if (wv < 7) {
            const int i = wv * 64 + lane;
            unsigned long long bb = __ballot(i < NQ && Rmas[b * NQ + i] != 0.0f);
            if (lane == 0) {
                ((unsigned*)(smem + MKB_OFF))[2 * wv]     = (unsigned)bb;
                ((unsigned*)(smem + MKB_OFF))[2 * wv + 1] = (unsigned)(bb >> 32);
            }
        }
        // zero-pad V^T permuted block 12 upper halves (orig k 400..415):
        // per row: bytes 768 + {8..15, 24..31, 40..47, 56..63}
        if (tid < 256) {
            const int r = tid >> 2, c = tid & 3;
            *(f16x4*)(smem + VT_OFF + r * 848 + 768 + c * 16 + 8) = (f16x4){0, 0, 0, 0};
        }
    }
    __syncthreads();

    const float* Rbh = R + (size_t)b * NQ * DMODEL + h * 64;

    // ---------- phase 1: QKV projections; K,V^T -> LDS; own Q tiles -> registers ----------
    f16x8 qreg[4][2];
    const int QSw = QS_OFF + wv * 2048;
    #pragma unroll
    for (int tt = 0; tt < 4; ++tt) {
        const int t = wv + 8 * tt;
        if (t < 25) {
            const float* rp = Rbh + (size_t)(t * 16 + q16) * DMODEL + g * 8;
            f16x8 af0 = cvt8(rp);
            f16x8 af1 = cvt8(rp + 32);
            #pragma unroll
            for (int m = 0; m < 3; ++m) {
                #pragma unroll
                for (int cg = 0; cg < 4; ++cg) {
                    const int col = cg * 16 + q16;
                    const float bb = *(const float*)(smem + BIAS_OFF + (m * 64 + col) * 4);
                    f32x4 acc = {bb, bb, bb, bb};
                    f16x8 wb0 = *(const f16x8*)(smem + W_OFF + m * 9216 + col * 144 + g * 16);
                    f16x8 wb1 = *(const f16x8*)(smem + W_OFF + m * 9216 + col * 144 + 64 + g * 16);
                    acc = MFMA16(af0, wb0, acc, 0, 0, 0);
                    acc = MFMA16(af1, wb1, acc, 0, 0, 0);
                    if (m == 0) {
                        // Q -> wave-private transpose scratch (swizzled 128B rows)
                        #pragma unroll
                        for (int r = 0; r < 4; ++r) {
                            const int rr = 4 * g + r;
                            *(_Float16*)(smem + QSw + rr * 128 + ((col * 2) ^ ((rr & 7) << 4))) =
                                (_Float16)acc[r];
                        }
                    } else if (m == 1) {
                        // K row-major, swizzled
                        #pragma unroll
                        for (int r = 0; r < 4; ++r) {
                            const int kk = t * 16 + 4 * g + r;
                            *(_Float16*)(smem + K_OFF + kk * 128 + ((col * 2) ^ ((kk & 7) << 4))) =
                                (_Float16)acc[r];
                        }
                    } else {
                        // V^T with block-permuted k order: k=16t+4g+{0..3} lands at
                        // byte (t>>1)*64 + g*16 + (t&1)*8 within row `col`
                        f16x4 hv;
                        hv[0]=(_Float16)acc[0]; hv[1]=(_Float16)acc[1];
                        hv[2]=(_Float16)acc[2]; hv[3]=(_Float16)acc[3];
                        *(f16x4*)(smem + VT_OFF + col * 848 + (t >> 1) * 64 + g * 16 + (t & 1) * 8) = hv;
                    }
                }
            }
            asm volatile("s_waitcnt lgkmcnt(0)" ::: "memory");
            qreg[tt][0] = *(const f16x8*)(smem + QSw + q16 * 128 + ((g * 16)      ^ ((q16 & 7) << 4)));
            qreg[tt][1] = *(const f16x8*)(smem + QSw + q16 * 128 + ((64 + g * 16) ^ ((q16 & 7) << 4)));
        }
    }
    __syncthreads();

    // ---------- phase 2: attention, P fully register-resident ----------
    unsigned mkw[13];
    #pragma unroll
    for (int i = 0; i < 13; ++i) mkw[i] = ((const unsigned*)(smem + MKB_OFF))[i];

    #pragma unroll
    for (int ti = 0; ti < 4; ++ti) {
        const int qt = wv + 8 * ti;
        if (qt < 25) {
            const float mq = *(const float*)(smem + MAS_OFF + (qt * 16 + q16) * 4);

            // swapped QK^T: lane (g,q16) accumulates S[q16][16kt+4g+r]
            f32x4 a[25];
            #pragma unroll
            for (int kt = 0; kt < 25; ++kt) {
                const int krow = kt * 16 + q16;
                f16x8 kf0 = *(const f16x8*)(smem + K_OFF + krow * 128 + ((g * 16)      ^ ((krow & 7) << 4)));
                f16x8 kf1 = *(const f16x8*)(smem + K_OFF + krow * 128 + ((64 + g * 16) ^ ((krow & 7) << 4)));
                f32x4 acc = {0.f, 0.f, 0.f, 0.f};
                acc = MFMA16(kf0, qreg[ti][0], acc, 0, 0, 0);
                acc = MFMA16(kf1, qreg[ti][1], acc, 0, 0, 0);
                a[kt] = acc;
            }

            // mask (bitmask penalty) + scale, row max (row is lane-local!)
            float pm = -3e38f;
            #pragma unroll
            for (int kt = 0; kt < 25; ++kt) {
                const unsigned wsh = mkw[kt >> 1] >> (((kt & 1) << 4) + 4 * g);
                #pragma unroll
                for (int r = 0; r < 4; ++r) {
                    float xx = a[kt][r] * SCL;
                    if (!((wsh >> r) & 1u)) xx -= PEN;
                    a[kt][r] = xx;
                    pm = fmaxf(pm, xx);
                }
            }
            pm = fmaxf(pm, __shfl_xor(pm, 16));
            pm = fmaxf(pm, __shfl_xor(pm, 32));

            // exp2 + row sum; pack P to f16 in registers
            float ps = 0.f;
            f16x4 ph[26];
            #pragma unroll
            for (int kt = 0; kt < 25; ++kt) {
                #pragma unroll
                for (int r = 0; r < 4; ++r) {
                    const float e = __builtin_amdgcn_exp2f(a[kt][r] - pm);
                    ps += e;
                    ph[kt][r] = (_Float16)e;
                }
            }
            ph[25] = (f16x4){0, 0, 0, 0};
            ps += __shfl_xor(ps, 16);
            ps += __shfl_xor(ps, 32);
            const float myrs = mq * __builtin_amdgcn_rcpf(ps);

            // PV: P-frag straight from registers (kappa matches permuted VT)
            f32x4 oc[4];
            #pragma unroll
            for (int cg = 0; cg < 4; ++cg) oc[cg] = (f32x4){0.f, 0.f, 0.f, 0.f};
            #pragma unroll
            for (int kc = 0; kc < 13; ++kc) {
                union { f16x4 hh[2]; f16x8 v; } pu;
                pu.hh[0] = ph[2 * kc];
                pu.hh[1] = ph[2 * kc + 1];
                const f16x8 pa = pu.v;
                #pragma unroll
                for (int cg = 0; cg < 4; ++cg) {
                    f16x8 vb = *(const f16x8*)(smem + VT_OFF + (cg * 16 + q16) * 848 + kc * 64 + g * 16);
                    oc[cg] = MFMA16(pa, vb, oc[cg], 0, 0, 0);
                }
            }

            // epilogue: redistribute row-scale via shfl, store fp32
            float rs[4];
            #pragma unroll
            for (int r = 0; r < 4; ++r) rs[r] = __shfl(myrs, 4 * g + r);
            float* op = out + (size_t)(b * NQ + qt * 16) * DMODEL + h * 64;
            #pragma unroll
            for (int r = 0; r < 4; ++r) {
                #pragma unroll
                for (int cg = 0; cg < 4; ++cg)
                    op[(4 * g + r) * DMODEL + cg * 16 + q16] = oc[cg][r] * rs[r];
            }
        }
    }
}

extern "C" void kernel_launch(void* const* d_in, const int* in_sizes, int n_in,
                              void* d_out, int out_size, void* d_ws, size_t ws_size,
                              hipStream_t stream) {
    const float* R    = (const float*)d_in[0];
    const float* Rmas = (const float*)d_in[1];
    const float* Wq   = (const float*)d_in[2];
    const float* bq   = (const float*)d_in[3];
    const float* Wk   = (const float*)d_in[4];
    const float* bk   = (const float*)d_in[5];
    const float* Wv   = (const float*)d_in[6];
    const float* bv   = (const float*)d_in[7];
    float* out = (float*)d_out;

    (void)hipFuncSetAttribute(reinterpret_cast<const void*>(attn_fused),
                              hipFuncAttributeMaxDynamicSharedMemorySize, SMEM_BYTES);
    attn_fused<<<dim3(384), dim3(512), SMEM_BYTES, stream>>>(R, Rmas, Wq, bq, Wk, bk, Wv, bv, out);
}